// Round 1
// baseline (178.677 us; speedup 1.0000x reference)
//
#include <hip/hip_runtime.h>
#include <hip/hip_bf16.h>

typedef __bf16 bf16_t;
typedef __attribute__((ext_vector_type(8))) __bf16 bf16x8;
typedef __attribute__((ext_vector_type(4))) float f32x4;

#define GLDS16(g, l) __builtin_amdgcn_global_load_lds( \
    (const __attribute__((address_space(1))) unsigned int*)(g), \
    (__attribute__((address_space(3))) unsigned int*)(l), 16, 0, 0)

// ---------------------------------------------------------------------------
// Kernel 1: convert Wq/Wk/Wv/Wp (f32 [256k][256n]) -> bf16 transposed [n][k]
// ---------------------------------------------------------------------------
__global__ __launch_bounds__(256) void wtr_kernel(
    const float* __restrict__ Wq, const float* __restrict__ Wk,
    const float* __restrict__ Wv, const float* __restrict__ Wp,
    bf16_t* __restrict__ Wt)
{
  const int idx = blockIdx.x * 256 + threadIdx.x;   // 0 .. 262143
  const int mat = idx >> 16;
  const int e   = idx & 65535;
  const int k   = e >> 8;
  const int n   = e & 255;
  const float* W = (mat == 0) ? Wq : (mat == 1) ? Wk : (mat == 2) ? Wv : Wp;
  Wt[(size_t)mat * 65536 + n * 256 + k] = (bf16_t)W[e];  // e == k*256+n
}

// ---------------------------------------------------------------------------
// Kernel 2: LayerNorm, f32 -> bf16. One wave per token (256 ch = 64 lanes x4).
// ---------------------------------------------------------------------------
__global__ __launch_bounds__(256) void ln_kernel(
    const float* __restrict__ x, const float* __restrict__ gamma,
    const float* __restrict__ beta, bf16_t* __restrict__ Xln)
{
  const int wave = threadIdx.x >> 6, lane = threadIdx.x & 63;
  const int tok = blockIdx.x * 4 + wave;
  const float4 v = *reinterpret_cast<const float4*>(x + (size_t)tok * 256 + lane * 4);
  float s1 = v.x + v.y + v.z + v.w;
  float s2 = v.x*v.x + v.y*v.y + v.z*v.z + v.w*v.w;
  #pragma unroll
  for (int off = 1; off < 64; off <<= 1) {
    s1 += __shfl_xor(s1, off);
    s2 += __shfl_xor(s2, off);
  }
  const float mean = s1 * (1.0f/256.0f);
  const float var  = s2 * (1.0f/256.0f) - mean*mean;
  const float rstd = rsqrtf(var + 1e-5f);
  const float4 g  = *reinterpret_cast<const float4*>(gamma + lane*4);
  const float4 be = *reinterpret_cast<const float4*>(beta  + lane*4);
  union { bf16_t h4[4]; unsigned long long u; } pk;
  pk.h4[0] = (bf16_t)((v.x-mean)*rstd*g.x + be.x);
  pk.h4[1] = (bf16_t)((v.y-mean)*rstd*g.y + be.y);
  pk.h4[2] = (bf16_t)((v.z-mean)*rstd*g.z + be.z);
  pk.h4[3] = (bf16_t)((v.w-mean)*rstd*g.w + be.w);
  *reinterpret_cast<unsigned long long*>(Xln + (size_t)tok*256 + lane*4) = pk.u;
}

// ---------------------------------------------------------------------------
// Kernel 3/5: bf16 MFMA GEMM, BM=128 BN=128 BK=64, 4 waves (2x2), K=256.
// MODE 0: A=Xln, B selects Wq/Wk/Wv by blockIdx.y; writes Qb/Kb (token-major)
//         or Vt (transposed [b][h][d][n]) for the V matrix.
// MODE 1: A=Yb, B=Wpt; writes f32 out + bias.
// LDS tiles XOR-swizzled (byte ^= (row&7)<<4) via pre-swizzled global source.
// ---------------------------------------------------------------------------
template<int MODE>
__global__ __launch_bounds__(256) void gemm_kernel(
    const bf16_t* __restrict__ A, const bf16_t* __restrict__ Wt,
    const float* __restrict__ b0, const float* __restrict__ b1,
    const float* __restrict__ b2,
    bf16_t* __restrict__ Qb, bf16_t* __restrict__ Kb, bf16_t* __restrict__ Vt,
    float* __restrict__ Fout)
{
  __shared__ __align__(16) bf16_t As[128*64];
  __shared__ __align__(16) bf16_t Bs[128*64];
  const int tid  = threadIdx.x;
  const int lane = tid & 63, wave = tid >> 6;
  const int lg = lane >> 4, li = lane & 15;
  const int wm = wave >> 1, wn = wave & 1;
  const int mt = blockIdx.x;
  const int nt = blockIdx.y;
  int mat, nbase;
  const bf16_t* Bm;
  if (MODE == 0) { mat = nt >> 1; nbase = (nt & 1) * 128; Bm = Wt + (size_t)mat * 65536; }
  else           { mat = 3;       nbase = nt * 128;       Bm = Wt; }

  f32x4 acc[4][4] = {};

  for (int kt = 0; kt < 4; ++kt) {
    __syncthreads();
    #pragma unroll
    for (int i = 0; i < 4; ++i) {
      const int idx = i*256 + tid;
      const int row = idx >> 3, ck = idx & 7;
      const int cs = ck ^ (row & 7);
      GLDS16(A + (size_t)(mt*128 + row)*256 + kt*64 + cs*8, As + idx*8);
    }
    #pragma unroll
    for (int i = 0; i < 4; ++i) {
      const int idx = i*256 + tid;
      const int row = idx >> 3, ck = idx & 7;
      const int cs = ck ^ (row & 7);
      GLDS16(Bm + (size_t)(nbase + row)*256 + kt*64 + cs*8, Bs + idx*8);
    }
    __syncthreads();
    #pragma unroll
    for (int kk = 0; kk < 2; ++kk) {
      bf16x8 af[4], bfv[4];
      #pragma unroll
      for (int mi = 0; mi < 4; ++mi) {
        const int row = wm*64 + mi*16 + li;
        const int c = (kk*4 + lg) ^ (row & 7);
        af[mi] = *reinterpret_cast<const bf16x8*>(As + row*64 + c*8);
      }
      #pragma unroll
      for (int ni = 0; ni < 4; ++ni) {
        const int row = wn*64 + ni*16 + li;
        const int c = (kk*4 + lg) ^ (row & 7);
        bfv[ni] = *reinterpret_cast<const bf16x8*>(Bs + row*64 + c*8);
      }
      #pragma unroll
      for (int mi = 0; mi < 4; ++mi)
        #pragma unroll
        for (int ni = 0; ni < 4; ++ni)
          acc[mi][ni] = __builtin_amdgcn_mfma_f32_16x16x32_bf16(af[mi], bfv[ni], acc[mi][ni], 0, 0, 0);
    }
  }

  if (MODE == 0) {
    const float* bias = (mat == 0) ? b0 : (mat == 1) ? b1 : b2;
    if (mat < 2) {
      bf16_t* Out = (mat == 0) ? Qb : Kb;
      #pragma unroll
      for (int mi = 0; mi < 4; ++mi)
        #pragma unroll
        for (int ni = 0; ni < 4; ++ni) {
          const int col = nbase + wn*64 + ni*16 + li;
          const float bb = bias[col];
          #pragma unroll
          for (int r = 0; r < 4; ++r) {
            const int row = mt*128 + wm*64 + mi*16 + lg*4 + r;
            Out[(size_t)row*256 + col] = (bf16_t)(acc[mi][ni][r] + bb);
          }
        }
    } else {
      // V: write transposed Vt[b][h][d][n], 4 consecutive tokens -> 8B store
      #pragma unroll
      for (int mi = 0; mi < 4; ++mi)
        #pragma unroll
        for (int ni = 0; ni < 4; ++ni) {
          const int col = nbase + wn*64 + ni*16 + li;
          const int hh = col >> 5, dd = col & 31;
          const float bb = bias[col];
          const int row0 = mt*128 + wm*64 + mi*16 + lg*4;
          const int bi = row0 >> 10, nn = row0 & 1023;
          union { bf16_t h4[4]; unsigned long long u; } pk;
          #pragma unroll
          for (int r = 0; r < 4; ++r) pk.h4[r] = (bf16_t)(acc[mi][ni][r] + bb);
          *reinterpret_cast<unsigned long long*>(
              Vt + ((size_t)(bi*8 + hh)*32 + dd)*1024 + nn) = pk.u;
        }
    }
  } else {
    #pragma unroll
    for (int mi = 0; mi < 4; ++mi)
      #pragma unroll
      for (int ni = 0; ni < 4; ++ni) {
        const int col = nbase + wn*64 + ni*16 + li;
        const float bb = b0[col];
        #pragma unroll
        for (int r = 0; r < 4; ++r) {
          const int row = mt*128 + wm*64 + mi*16 + lg*4 + r;
          Fout[(size_t)row*256 + col] = acc[mi][ni][r] + bb;
        }
      }
  }
}

// ---------------------------------------------------------------------------
// Kernel 4: flash attention. Block = (b,h, 64 q-rows), 4 waves x 16 rows.
// Per 64-key chunk: QK^T (4 MFMA, frags from L2-hot global), f32 online
// softmax (16-lane shfl reduce), P -> bf16 via padded per-wave LDS bounce,
// PV (4 MFMA, V from transposed Vt).
// ---------------------------------------------------------------------------
__global__ __launch_bounds__(256) void attn_kernel(
    const bf16_t* __restrict__ Qb, const bf16_t* __restrict__ Kb,
    const bf16_t* __restrict__ Vt, bf16_t* __restrict__ Yb)
{
  __shared__ __align__(16) bf16_t plds[4][16][72];   // 72: pad to break bank conflicts
  const int tid  = threadIdx.x;
  const int wave = tid >> 6, lane = tid & 63;
  const int lg = lane >> 4, li = lane & 15;
  const int qt = blockIdx.x;            // 16 q-tiles of 64 rows
  const int bh = blockIdx.y;            // b*8 + h
  const int b  = bh >> 3, hh = bh & 7;
  const int tok0 = b*1024 + qt*64 + wave*16;

  const bf16x8 qf = *reinterpret_cast<const bf16x8*>(
      Qb + (size_t)(tok0 + li)*256 + hh*32 + lg*8);

  const f32x4 fz = {0.f, 0.f, 0.f, 0.f};
  f32x4 acc0 = fz, acc1 = fz;
  float mrow[4] = {-1e30f, -1e30f, -1e30f, -1e30f};
  float lrow[4] = {0.f, 0.f, 0.f, 0.f};
  const float scale = 0.1767766952966369f;   // 1/sqrt(32)

  for (int mc = 0; mc < 16; ++mc) {
    const int m0 = b*1024 + mc*64;
    f32x4 s[4];
    #pragma unroll
    for (int ct = 0; ct < 4; ++ct) {
      const bf16x8 kf = *reinterpret_cast<const bf16x8*>(
          Kb + (size_t)(m0 + ct*16 + li)*256 + hh*32 + lg*8);
      s[ct] = __builtin_amdgcn_mfma_f32_16x16x32_bf16(qf, kf, fz, 0, 0, 0);
    }
    #pragma unroll
    for (int r = 0; r < 4; ++r) {
      float mx = fmaxf(fmaxf(s[0][r], s[1][r]), fmaxf(s[2][r], s[3][r]));
      mx = fmaxf(mx, __shfl_xor(mx, 1));
      mx = fmaxf(mx, __shfl_xor(mx, 2));
      mx = fmaxf(mx, __shfl_xor(mx, 4));
      mx = fmaxf(mx, __shfl_xor(mx, 8));
      const float mnew = fmaxf(mrow[r], mx * scale);
      const float sf = __expf(mrow[r] - mnew);
      float sum = 0.f;
      #pragma unroll
      for (int ct = 0; ct < 4; ++ct) {
        const float p = __expf(s[ct][r]*scale - mnew);
        s[ct][r] = p;
        sum += p;
      }
      sum += __shfl_xor(sum, 1);
      sum += __shfl_xor(sum, 2);
      sum += __shfl_xor(sum, 4);
      sum += __shfl_xor(sum, 8);
      lrow[r] = lrow[r]*sf + sum;
      mrow[r] = mnew;
      acc0[r] *= sf;
      acc1[r] *= sf;
      #pragma unroll
      for (int ct = 0; ct < 4; ++ct)
        plds[wave][lg*4 + r][ct*16 + li] = (bf16_t)s[ct][r];
    }
    // own-wave LDS RAW: drain DS queue before fragment reads (no barrier needed,
    // each wave reads only its own region)
    asm volatile("s_waitcnt lgkmcnt(0)" ::: "memory");
    #pragma unroll
    for (int kk = 0; kk < 2; ++kk) {
      const bf16x8 pf = *reinterpret_cast<const bf16x8*>(&plds[wave][li][kk*32 + lg*8]);
      const bf16x8 vf0 = *reinterpret_cast<const bf16x8*>(
          Vt + ((size_t)bh*32 + li)*1024 + mc*64 + kk*32 + lg*8);
      acc0 = __builtin_amdgcn_mfma_f32_16x16x32_bf16(pf, vf0, acc0, 0, 0, 0);
      const bf16x8 vf1 = *reinterpret_cast<const bf16x8*>(
          Vt + ((size_t)bh*32 + 16 + li)*1024 + mc*64 + kk*32 + lg*8);
      acc1 = __builtin_amdgcn_mfma_f32_16x16x32_bf16(pf, vf1, acc1, 0, 0, 0);
    }
  }

  #pragma unroll
  for (int r = 0; r < 4; ++r) {
    const float inv = 1.0f / lrow[r];
    const int tok = tok0 + lg*4 + r;
    Yb[(size_t)tok*256 + hh*32 + li]      = (bf16_t)(acc0[r]*inv);
    Yb[(size_t)tok*256 + hh*32 + 16 + li] = (bf16_t)(acc1[r]*inv);
  }
}

// ---------------------------------------------------------------------------
extern "C" void kernel_launch(void* const* d_in, const int* in_sizes, int n_in,
                              void* d_out, int out_size, void* d_ws, size_t ws_size,
                              hipStream_t stream) {
  const float* x     = (const float*)d_in[0];
  const float* gamma = (const float*)d_in[1];
  const float* beta  = (const float*)d_in[2];
  const float* Wq    = (const float*)d_in[3];
  const float* bq    = (const float*)d_in[4];
  const float* Wk    = (const float*)d_in[5];
  const float* bk    = (const float*)d_in[6];
  const float* Wv    = (const float*)d_in[7];
  const float* bv    = (const float*)d_in[8];
  const float* Wp    = (const float*)d_in[9];
  const float* bp    = (const float*)d_in[10];
  float* out = (float*)d_out;

  char* ws = (char*)d_ws;
  bf16_t* Wt  = (bf16_t*)(ws);              // 4 * 65536 bf16 = 512 KB
  bf16_t* Xln = (bf16_t*)(ws + 524288);     // 16384*256 bf16 = 8 MB
  bf16_t* Qb  = (bf16_t*)(ws + 8912896);    // 8 MB
  bf16_t* Kb  = (bf16_t*)(ws + 17301504);   // 8 MB
  bf16_t* Vt  = (bf16_t*)(ws + 25690112);   // 8 MB  (total 32.5 MB)
  bf16_t* Yb  = Xln;                        // alias: Xln dead after QKV GEMM

  wtr_kernel<<<1024, 256, 0, stream>>>(Wq, Wk, Wv, Wp, Wt);
  ln_kernel<<<4096, 256, 0, stream>>>(x, gamma, beta, Xln);
  gemm_kernel<0><<<dim3(128, 6), 256, 0, stream>>>(
      Xln, Wt, bq, bk, bv, Qb, Kb, Vt, nullptr);
  attn_kernel<<<dim3(16, 128), 256, 0, stream>>>(Qb, Kb, Vt, Yb);
  gemm_kernel<1><<<dim3(128, 2), 256, 0, stream>>>(
      Yb, Wt + 3*65536, bp, nullptr, nullptr, nullptr, nullptr, nullptr, out);
}

// Round 2
// 177.212 us; speedup vs baseline: 1.0083x; 1.0083x over previous
//
#include <hip/hip_runtime.h>
#include <hip/hip_bf16.h>

typedef __bf16 bf16_t;
typedef __attribute__((ext_vector_type(8))) __bf16 bf16x8;
typedef __attribute__((ext_vector_type(4))) float f32x4;

#define GLDS16(g, l) __builtin_amdgcn_global_load_lds( \
    (const __attribute__((address_space(1))) unsigned int*)(g), \
    (__attribute__((address_space(3))) unsigned int*)(l), 16, 0, 0)

__device__ __forceinline__ float fexp2(float x) {
#if __has_builtin(__builtin_amdgcn_exp2f)
  return __builtin_amdgcn_exp2f(x);
#else
  return exp2f(x);
#endif
}

// Q pre-scale: 1/sqrt(32) * log2(e), folded into QKV-GEMM epilogue so the
// attention kernel can use raw v_exp_f32 (2^x) with no per-score multiply.
#define QSCALE (0.17677669529663688f * 1.4426950408889634f)

// ---------------------------------------------------------------------------
// Kernel 1: convert Wq/Wk/Wv/Wp (f32 [256k][256n]) -> bf16 transposed [n][k]
// ---------------------------------------------------------------------------
__global__ __launch_bounds__(256) void wtr_kernel(
    const float* __restrict__ Wq, const float* __restrict__ Wk,
    const float* __restrict__ Wv, const float* __restrict__ Wp,
    bf16_t* __restrict__ Wt)
{
  const int idx = blockIdx.x * 256 + threadIdx.x;   // 0 .. 262143
  const int mat = idx >> 16;
  const int e   = idx & 65535;
  const int k   = e >> 8;
  const int n   = e & 255;
  const float* W = (mat == 0) ? Wq : (mat == 1) ? Wk : (mat == 2) ? Wv : Wp;
  Wt[(size_t)mat * 65536 + n * 256 + k] = (bf16_t)W[e];  // e == k*256+n
}

// ---------------------------------------------------------------------------
// Kernel 2: LayerNorm, f32 -> bf16. One wave per token (256 ch = 64 lanes x4).
// ---------------------------------------------------------------------------
__global__ __launch_bounds__(256) void ln_kernel(
    const float* __restrict__ x, const float* __restrict__ gamma,
    const float* __restrict__ beta, bf16_t* __restrict__ Xln)
{
  const int wave = threadIdx.x >> 6, lane = threadIdx.x & 63;
  const int tok = blockIdx.x * 4 + wave;
  const float4 v = *reinterpret_cast<const float4*>(x + (size_t)tok * 256 + lane * 4);
  float s1 = v.x + v.y + v.z + v.w;
  float s2 = v.x*v.x + v.y*v.y + v.z*v.z + v.w*v.w;
  #pragma unroll
  for (int off = 1; off < 64; off <<= 1) {
    s1 += __shfl_xor(s1, off);
    s2 += __shfl_xor(s2, off);
  }
  const float mean = s1 * (1.0f/256.0f);
  const float var  = s2 * (1.0f/256.0f) - mean*mean;
  const float rstd = rsqrtf(var + 1e-5f);
  const float4 g  = *reinterpret_cast<const float4*>(gamma + lane*4);
  const float4 be = *reinterpret_cast<const float4*>(beta  + lane*4);
  union { bf16_t h4[4]; unsigned long long u; } pk;
  pk.h4[0] = (bf16_t)((v.x-mean)*rstd*g.x + be.x);
  pk.h4[1] = (bf16_t)((v.y-mean)*rstd*g.y + be.y);
  pk.h4[2] = (bf16_t)((v.z-mean)*rstd*g.z + be.z);
  pk.h4[3] = (bf16_t)((v.w-mean)*rstd*g.w + be.w);
  *reinterpret_cast<unsigned long long*>(Xln + (size_t)tok*256 + lane*4) = pk.u;
}

// ---------------------------------------------------------------------------
// Kernel 3/5: bf16 MFMA GEMM, BM=128 BN=128 BK=64, 4 waves (2x2), K=256.
// MODE 0: A=Xln, B selects Wq/Wk/Wv by blockIdx.y; writes Qb (pre-scaled by
//         QSCALE) / Kb (token-major) or Vt (transposed [b][h][d][n]).
// MODE 1: A=Yb, B=Wpt; writes f32 out + bias.
// LDS tiles XOR-swizzled (byte ^= (row&7)<<4) via pre-swizzled global source.
// ---------------------------------------------------------------------------
template<int MODE>
__global__ __launch_bounds__(256) void gemm_kernel(
    const bf16_t* __restrict__ A, const bf16_t* __restrict__ Wt,
    const float* __restrict__ b0, const float* __restrict__ b1,
    const float* __restrict__ b2,
    bf16_t* __restrict__ Qb, bf16_t* __restrict__ Kb, bf16_t* __restrict__ Vt,
    float* __restrict__ Fout)
{
  __shared__ __align__(16) bf16_t As[128*64];
  __shared__ __align__(16) bf16_t Bs[128*64];
  const int tid  = threadIdx.x;
  const int lane = tid & 63, wave = tid >> 6;
  const int lg = lane >> 4, li = lane & 15;
  const int wm = wave >> 1, wn = wave & 1;
  const int mt = blockIdx.x;
  const int nt = blockIdx.y;
  int mat, nbase;
  const bf16_t* Bm;
  if (MODE == 0) { mat = nt >> 1; nbase = (nt & 1) * 128; Bm = Wt + (size_t)mat * 65536; }
  else           { mat = 3;       nbase = nt * 128;       Bm = Wt; }

  f32x4 acc[4][4] = {};

  for (int kt = 0; kt < 4; ++kt) {
    __syncthreads();
    #pragma unroll
    for (int i = 0; i < 4; ++i) {
      const int idx = i*256 + tid;
      const int row = idx >> 3, ck = idx & 7;
      const int cs = ck ^ (row & 7);
      GLDS16(A + (size_t)(mt*128 + row)*256 + kt*64 + cs*8, As + idx*8);
    }
    #pragma unroll
    for (int i = 0; i < 4; ++i) {
      const int idx = i*256 + tid;
      const int row = idx >> 3, ck = idx & 7;
      const int cs = ck ^ (row & 7);
      GLDS16(Bm + (size_t)(nbase + row)*256 + kt*64 + cs*8, Bs + idx*8);
    }
    __syncthreads();
    #pragma unroll
    for (int kk = 0; kk < 2; ++kk) {
      bf16x8 af[4], bfv[4];
      #pragma unroll
      for (int mi = 0; mi < 4; ++mi) {
        const int row = wm*64 + mi*16 + li;
        const int c = (kk*4 + lg) ^ (row & 7);
        af[mi] = *reinterpret_cast<const bf16x8*>(As + row*64 + c*8);
      }
      #pragma unroll
      for (int ni = 0; ni < 4; ++ni) {
        const int row = wn*64 + ni*16 + li;
        const int c = (kk*4 + lg) ^ (row & 7);
        bfv[ni] = *reinterpret_cast<const bf16x8*>(Bs + row*64 + c*8);
      }
      #pragma unroll
      for (int mi = 0; mi < 4; ++mi)
        #pragma unroll
        for (int ni = 0; ni < 4; ++ni)
          acc[mi][ni] = __builtin_amdgcn_mfma_f32_16x16x32_bf16(af[mi], bfv[ni], acc[mi][ni], 0, 0, 0);
    }
  }

  if (MODE == 0) {
    const float* bias = (mat == 0) ? b0 : (mat == 1) ? b1 : b2;
    if (mat < 2) {
      bf16_t* Out = (mat == 0) ? Qb : Kb;
      const float osc = (mat == 0) ? QSCALE : 1.0f;
      #pragma unroll
      for (int mi = 0; mi < 4; ++mi)
        #pragma unroll
        for (int ni = 0; ni < 4; ++ni) {
          const int col = nbase + wn*64 + ni*16 + li;
          const float bb = bias[col];
          #pragma unroll
          for (int r = 0; r < 4; ++r) {
            const int row = mt*128 + wm*64 + mi*16 + lg*4 + r;
            Out[(size_t)row*256 + col] = (bf16_t)((acc[mi][ni][r] + bb) * osc);
          }
        }
    } else {
      // V: write transposed Vt[b][h][d][n], 4 consecutive tokens -> 8B store
      #pragma unroll
      for (int mi = 0; mi < 4; ++mi)
        #pragma unroll
        for (int ni = 0; ni < 4; ++ni) {
          const int col = nbase + wn*64 + ni*16 + li;
          const int hh = col >> 5, dd = col & 31;
          const float bb = bias[col];
          const int row0 = mt*128 + wm*64 + mi*16 + lg*4;
          const int bi = row0 >> 10, nn = row0 & 1023;
          union { bf16_t h4[4]; unsigned long long u; } pk;
          #pragma unroll
          for (int r = 0; r < 4; ++r) pk.h4[r] = (bf16_t)(acc[mi][ni][r] + bb);
          *reinterpret_cast<unsigned long long*>(
              Vt + ((size_t)(bi*8 + hh)*32 + dd)*1024 + nn) = pk.u;
        }
    }
  } else {
    #pragma unroll
    for (int mi = 0; mi < 4; ++mi)
      #pragma unroll
      for (int ni = 0; ni < 4; ++ni) {
        const int col = nbase + wn*64 + ni*16 + li;
        const float bb = b0[col];
        #pragma unroll
        for (int r = 0; r < 4; ++r) {
          const int row = mt*128 + wm*64 + mi*16 + lg*4 + r;
          Fout[(size_t)row*256 + col] = acc[mi][ni][r] + bb;
        }
      }
  }
}

// ---------------------------------------------------------------------------
// Kernel 4: flash attention, swapped-operand form.
// Block = (b,h, 64 q-rows), 4 waves x 16 q-rows.
// S^T = mfma(K,Q): lane li owns q-row li; 16 k-scores live in regs
//   s[ct][r] = S[k=ct*16+lg*4+r][q=li]  -> row reductions are in-lane + 2 shfl.
// PV also swapped: acc = mfma(V^T, P^T) -> Y^T (row=d=lg*4+r, col=q=li), so
// m/l/rescale stay lane-local. P bounced through LDS as packed b64 writes.
// Grid: 1D 2048, decoded so all 16 q-tiles of a (b,h) share one XCD.
// ---------------------------------------------------------------------------
__global__ __launch_bounds__(256) void attn_kernel(
    const bf16_t* __restrict__ Qb, const bf16_t* __restrict__ Kb,
    const bf16_t* __restrict__ Vt, bf16_t* __restrict__ Yb)
{
  __shared__ __align__(16) bf16_t plds[4][16][72];   // [wave][q][k(64)+pad]
  const int tid  = threadIdx.x;
  const int wave = tid >> 6, lane = tid & 63;
  const int lg = lane >> 4, li = lane & 15;
  const int gid = blockIdx.x;
  const int qt = (gid >> 3) & 15;
  const int bh = ((gid >> 7) << 3) | (gid & 7);   // blocks of one bh: same XCD
  const int b  = bh >> 3, hh = bh & 7;
  const int tok0 = b*1024 + qt*64 + wave*16;

  // B-operand: Q^T[d][q], lane holds q=li, d = lg*8..+7 (pre-scaled by QSCALE)
  const bf16x8 qf = *reinterpret_cast<const bf16x8*>(
      Qb + (size_t)(tok0 + li)*256 + hh*32 + lg*8);

  const f32x4 fz = {0.f, 0.f, 0.f, 0.f};
  f32x4 acc0 = fz, acc1 = fz;                     // Y^T: d=lg*4+r (+16), q=li
  float mrow = -1e30f, lrow = 0.f;                // per-lane: q = li

  for (int mc = 0; mc < 16; ++mc) {
    const int m0 = b*1024 + mc*64;
    f32x4 s[4];
    #pragma unroll
    for (int ct = 0; ct < 4; ++ct) {
      // A-operand: K rows = k-tokens
      const bf16x8 kf = *reinterpret_cast<const bf16x8*>(
          Kb + (size_t)(m0 + ct*16 + li)*256 + hh*32 + lg*8);
      s[ct] = __builtin_amdgcn_mfma_f32_16x16x32_bf16(kf, qf, fz, 0, 0, 0);
    }
    // ---- per-lane softmax over the 16 scores (q = li) ----
    float mx01 = fmaxf(fmaxf(s[0][0], s[0][1]), fmaxf(s[0][2], s[0][3]));
    float mx23 = fmaxf(fmaxf(s[1][0], s[1][1]), fmaxf(s[1][2], s[1][3]));
    float mx45 = fmaxf(fmaxf(s[2][0], s[2][1]), fmaxf(s[2][2], s[2][3]));
    float mx67 = fmaxf(fmaxf(s[3][0], s[3][1]), fmaxf(s[3][2], s[3][3]));
    float mx = fmaxf(fmaxf(mx01, mx23), fmaxf(mx45, mx67));
    mx = fmaxf(mx, __shfl_xor(mx, 16));
    mx = fmaxf(mx, __shfl_xor(mx, 32));
    const float mnew = fmaxf(mrow, mx);
    const float sf = fexp2(mrow - mnew);
    float psum[4];
    #pragma unroll
    for (int ct = 0; ct < 4; ++ct) {
      #pragma unroll
      for (int r = 0; r < 4; ++r)
        s[ct][r] = fexp2(s[ct][r] - mnew);
      psum[ct] = (s[ct][0] + s[ct][1]) + (s[ct][2] + s[ct][3]);
    }
    float sum = (psum[0] + psum[1]) + (psum[2] + psum[3]);
    sum += __shfl_xor(sum, 16);
    sum += __shfl_xor(sum, 32);
    lrow = lrow*sf + sum;
    mrow = mnew;
    #pragma unroll
    for (int r = 0; r < 4; ++r) { acc0[r] *= sf; acc1[r] *= sf; }
    // ---- P^T -> LDS: lane li writes q-row li, k = ct*16+lg*4..+3 (8B) ----
    #pragma unroll
    for (int ct = 0; ct < 4; ++ct) {
      union { bf16_t h4[4]; unsigned long long u; } pk;
      #pragma unroll
      for (int r = 0; r < 4; ++r) pk.h4[r] = (bf16_t)s[ct][r];
      *reinterpret_cast<unsigned long long*>(&plds[wave][li][ct*16 + lg*4]) = pk.u;
    }
    asm volatile("s_waitcnt lgkmcnt(0)" ::: "memory");  // own-region RAW drain
    #pragma unroll
    for (int kk = 0; kk < 2; ++kk) {
      // B-operand: P^T[k][q], lane holds q=li, k = kk*32 + lg*8..+7
      const bf16x8 pf = *reinterpret_cast<const bf16x8*>(&plds[wave][li][kk*32 + lg*8]);
      // A-operand: V^T[d][k], lane holds d=li (+16), k-tokens contiguous
      const bf16x8 vf0 = *reinterpret_cast<const bf16x8*>(
          Vt + ((size_t)bh*32 + li)*1024 + mc*64 + kk*32 + lg*8);
      acc0 = __builtin_amdgcn_mfma_f32_16x16x32_bf16(vf0, pf, acc0, 0, 0, 0);
      const bf16x8 vf1 = *reinterpret_cast<const bf16x8*>(
          Vt + ((size_t)bh*32 + 16 + li)*1024 + mc*64 + kk*32 + lg*8);
      acc1 = __builtin_amdgcn_mfma_f32_16x16x32_bf16(vf1, pf, acc1, 0, 0, 0);
    }
  }

  const float inv = 1.0f / lrow;
  union { bf16_t h4[4]; unsigned long long u; } o0, o1;
  #pragma unroll
  for (int r = 0; r < 4; ++r) {
    o0.h4[r] = (bf16_t)(acc0[r]*inv);
    o1.h4[r] = (bf16_t)(acc1[r]*inv);
  }
  bf16_t* yp = Yb + (size_t)(tok0 + li)*256 + hh*32;
  *reinterpret_cast<unsigned long long*>(yp + lg*4)      = o0.u;
  *reinterpret_cast<unsigned long long*>(yp + 16 + lg*4) = o1.u;
}

// ---------------------------------------------------------------------------
extern "C" void kernel_launch(void* const* d_in, const int* in_sizes, int n_in,
                              void* d_out, int out_size, void* d_ws, size_t ws_size,
                              hipStream_t stream) {
  const float* x     = (const float*)d_in[0];
  const float* gamma = (const float*)d_in[1];
  const float* beta  = (const float*)d_in[2];
  const float* Wq    = (const float*)d_in[3];
  const float* bq    = (const float*)d_in[4];
  const float* Wk    = (const float*)d_in[5];
  const float* bk    = (const float*)d_in[6];
  const float* Wv    = (const float*)d_in[7];
  const float* bv    = (const float*)d_in[8];
  const float* Wp    = (const float*)d_in[9];
  const float* bp    = (const float*)d_in[10];
  float* out = (float*)d_out;

  char* ws = (char*)d_ws;
  bf16_t* Wt  = (bf16_t*)(ws);              // 4 * 65536 bf16 = 512 KB
  bf16_t* Xln = (bf16_t*)(ws + 524288);     // 16384*256 bf16 = 8 MB
  bf16_t* Qb  = (bf16_t*)(ws + 8912896);    // 8 MB
  bf16_t* Kb  = (bf16_t*)(ws + 17301504);   // 8 MB
  bf16_t* Vt  = (bf16_t*)(ws + 25690112);   // 8 MB  (total 32.5 MB)
  bf16_t* Yb  = Xln;                        // alias: Xln dead after QKV GEMM

  wtr_kernel<<<1024, 256, 0, stream>>>(Wq, Wk, Wv, Wp, Wt);
  ln_kernel<<<4096, 256, 0, stream>>>(x, gamma, beta, Xln);
  gemm_kernel<0><<<dim3(128, 6), 256, 0, stream>>>(
      Xln, Wt, bq, bk, bv, Qb, Kb, Vt, nullptr);
  attn_kernel<<<2048, 256, 0, stream>>>(Qb, Kb, Vt, Yb);
  gemm_kernel<1><<<dim3(128, 2), 256, 0, stream>>>(
      Yb, Wt + 3*65536, bp, nullptr, nullptr, nullptr, nullptr, nullptr, out);
}

// Round 3
// 159.931 us; speedup vs baseline: 1.1172x; 1.1081x over previous
//
#include <hip/hip_runtime.h>
#include <hip/hip_bf16.h>

typedef __bf16 bf16_t;
typedef __attribute__((ext_vector_type(8))) __bf16 bf16x8;
typedef __attribute__((ext_vector_type(4))) float f32x4;

#define GLDS16(g, l) __builtin_amdgcn_global_load_lds( \
    (const __attribute__((address_space(1))) unsigned int*)(g), \
    (__attribute__((address_space(3))) unsigned int*)(l), 16, 0, 0)

__device__ __forceinline__ float fexp2(float x) {
#if __has_builtin(__builtin_amdgcn_exp2f)
  return __builtin_amdgcn_exp2f(x);
#else
  return exp2f(x);
#endif
}

// Q pre-scale: 1/sqrt(32) * log2(e) folded into QKV-GEMM epilogue; attention
// softmax runs in the exp2 domain (raw v_exp_f32, no per-score multiply).
#define QSCALE (0.17677669529663688f * 1.4426950408889634f)

// ---------------------------------------------------------------------------
// Kernel 1: convert Wq/Wk/Wv/Wp (f32 [256k][256n]) -> bf16 transposed [n][k]
// ---------------------------------------------------------------------------
__global__ __launch_bounds__(256) void wtr_kernel(
    const float* __restrict__ Wq, const float* __restrict__ Wk,
    const float* __restrict__ Wv, const float* __restrict__ Wp,
    bf16_t* __restrict__ Wt)
{
  const int idx = blockIdx.x * 256 + threadIdx.x;   // 0 .. 262143
  const int mat = idx >> 16;
  const int e   = idx & 65535;
  const int k   = e >> 8;
  const int n   = e & 255;
  const float* W = (mat == 0) ? Wq : (mat == 1) ? Wk : (mat == 2) ? Wv : Wp;
  Wt[(size_t)mat * 65536 + n * 256 + k] = (bf16_t)W[e];  // e == k*256+n
}

// ---------------------------------------------------------------------------
// Kernel 2: LayerNorm, f32 -> bf16. One wave per token (256 ch = 64 lanes x4).
// ---------------------------------------------------------------------------
__global__ __launch_bounds__(256) void ln_kernel(
    const float* __restrict__ x, const float* __restrict__ gamma,
    const float* __restrict__ beta, bf16_t* __restrict__ Xln)
{
  const int wave = threadIdx.x >> 6, lane = threadIdx.x & 63;
  const int tok = blockIdx.x * 4 + wave;
  const float4 v = *reinterpret_cast<const float4*>(x + (size_t)tok * 256 + lane * 4);
  float s1 = v.x + v.y + v.z + v.w;
  float s2 = v.x*v.x + v.y*v.y + v.z*v.z + v.w*v.w;
  #pragma unroll
  for (int off = 1; off < 64; off <<= 1) {
    s1 += __shfl_xor(s1, off);
    s2 += __shfl_xor(s2, off);
  }
  const float mean = s1 * (1.0f/256.0f);
  const float var  = s2 * (1.0f/256.0f) - mean*mean;
  const float rstd = rsqrtf(var + 1e-5f);
  const float4 g  = *reinterpret_cast<const float4*>(gamma + lane*4);
  const float4 be = *reinterpret_cast<const float4*>(beta  + lane*4);
  union { bf16_t h4[4]; unsigned long long u; } pk;
  pk.h4[0] = (bf16_t)((v.x-mean)*rstd*g.x + be.x);
  pk.h4[1] = (bf16_t)((v.y-mean)*rstd*g.y + be.y);
  pk.h4[2] = (bf16_t)((v.z-mean)*rstd*g.z + be.z);
  pk.h4[3] = (bf16_t)((v.w-mean)*rstd*g.w + be.w);
  *reinterpret_cast<unsigned long long*>(Xln + (size_t)tok*256 + lane*4) = pk.u;
}

// ---------------------------------------------------------------------------
// Kernel 3/5: bf16 MFMA GEMM, BM=128 BN=128 BK=64, 4 waves (2x2), K=256.
// MODE 0: A=Xln, B selects Wq/Wk/Wv by blockIdx.y; writes Qb (pre-scaled by
//         QSCALE) / Kb (token-major) or Vt (transposed [b][h][d][n]).
// MODE 1: A=Yb, B=Wpt; writes f32 out + bias.
// LDS tiles XOR-swizzled (byte ^= (row&7)<<4) via pre-swizzled global source.
// ---------------------------------------------------------------------------
template<int MODE>
__global__ __launch_bounds__(256) void gemm_kernel(
    const bf16_t* __restrict__ A, const bf16_t* __restrict__ Wt,
    const float* __restrict__ b0, const float* __restrict__ b1,
    const float* __restrict__ b2,
    bf16_t* __restrict__ Qb, bf16_t* __restrict__ Kb, bf16_t* __restrict__ Vt,
    float* __restrict__ Fout)
{
  __shared__ __align__(16) bf16_t As[128*64];
  __shared__ __align__(16) bf16_t Bs[128*64];
  const int tid  = threadIdx.x;
  const int lane = tid & 63, wave = tid >> 6;
  const int lg = lane >> 4, li = lane & 15;
  const int wm = wave >> 1, wn = wave & 1;
  const int mt = blockIdx.x;
  const int nt = blockIdx.y;
  int mat, nbase;
  const bf16_t* Bm;
  if (MODE == 0) { mat = nt >> 1; nbase = (nt & 1) * 128; Bm = Wt + (size_t)mat * 65536; }
  else           { mat = 3;       nbase = nt * 128;       Bm = Wt; }

  f32x4 acc[4][4] = {};

  for (int kt = 0; kt < 4; ++kt) {
    __syncthreads();
    #pragma unroll
    for (int i = 0; i < 4; ++i) {
      const int idx = i*256 + tid;
      const int row = idx >> 3, ck = idx & 7;
      const int cs = ck ^ (row & 7);
      GLDS16(A + (size_t)(mt*128 + row)*256 + kt*64 + cs*8, As + idx*8);
    }
    #pragma unroll
    for (int i = 0; i < 4; ++i) {
      const int idx = i*256 + tid;
      const int row = idx >> 3, ck = idx & 7;
      const int cs = ck ^ (row & 7);
      GLDS16(Bm + (size_t)(nbase + row)*256 + kt*64 + cs*8, Bs + idx*8);
    }
    __syncthreads();
    #pragma unroll
    for (int kk = 0; kk < 2; ++kk) {
      bf16x8 af[4], bfv[4];
      #pragma unroll
      for (int mi = 0; mi < 4; ++mi) {
        const int row = wm*64 + mi*16 + li;
        const int c = (kk*4 + lg) ^ (row & 7);
        af[mi] = *reinterpret_cast<const bf16x8*>(As + row*64 + c*8);
      }
      #pragma unroll
      for (int ni = 0; ni < 4; ++ni) {
        const int row = wn*64 + ni*16 + li;
        const int c = (kk*4 + lg) ^ (row & 7);
        bfv[ni] = *reinterpret_cast<const bf16x8*>(Bs + row*64 + c*8);
      }
      #pragma unroll
      for (int mi = 0; mi < 4; ++mi)
        #pragma unroll
        for (int ni = 0; ni < 4; ++ni)
          acc[mi][ni] = __builtin_amdgcn_mfma_f32_16x16x32_bf16(af[mi], bfv[ni], acc[mi][ni], 0, 0, 0);
    }
  }

  if (MODE == 0) {
    const float* bias = (mat == 0) ? b0 : (mat == 1) ? b1 : b2;
    if (mat < 2) {
      bf16_t* Out = (mat == 0) ? Qb : Kb;
      const float osc = (mat == 0) ? QSCALE : 1.0f;
      #pragma unroll
      for (int mi = 0; mi < 4; ++mi)
        #pragma unroll
        for (int ni = 0; ni < 4; ++ni) {
          const int col = nbase + wn*64 + ni*16 + li;
          const float bb = bias[col];
          #pragma unroll
          for (int r = 0; r < 4; ++r) {
            const int row = mt*128 + wm*64 + mi*16 + lg*4 + r;
            Out[(size_t)row*256 + col] = (bf16_t)((acc[mi][ni][r] + bb) * osc);
          }
        }
    } else {
      // V: write transposed Vt[b][h][d][n], 4 consecutive tokens -> 8B store
      #pragma unroll
      for (int mi = 0; mi < 4; ++mi)
        #pragma unroll
        for (int ni = 0; ni < 4; ++ni) {
          const int col = nbase + wn*64 + ni*16 + li;
          const int hh = col >> 5, dd = col & 31;
          const float bb = bias[col];
          const int row0 = mt*128 + wm*64 + mi*16 + lg*4;
          const int bi = row0 >> 10, nn = row0 & 1023;
          union { bf16_t h4[4]; unsigned long long u; } pk;
          #pragma unroll
          for (int r = 0; r < 4; ++r) pk.h4[r] = (bf16_t)(acc[mi][ni][r] + bb);
          *reinterpret_cast<unsigned long long*>(
              Vt + ((size_t)(bi*8 + hh)*32 + dd)*1024 + nn) = pk.u;
        }
    }
  } else {
    #pragma unroll
    for (int mi = 0; mi < 4; ++mi)
      #pragma unroll
      for (int ni = 0; ni < 4; ++ni) {
        const int col = nbase + wn*64 + ni*16 + li;
        const float bb = b0[col];
        #pragma unroll
        for (int r = 0; r < 4; ++r) {
          const int row = mt*128 + wm*64 + mi*16 + lg*4 + r;
          Fout[(size_t)row*256 + col] = acc[mi][ni][r] + bb;
        }
      }
  }
}

// ---------------------------------------------------------------------------
// Kernel 4: flash attention, swapped-operand + defer-max + K-prefetch.
// Block = (b,h, 64 q-rows), 4 waves x 16 q-rows. Fully unrolled over the 16
// key chunks so the K double-buffer index is compile-time (no scratch).
// S^T = mfma(K,Q): lane li owns q-row li; softmax is per-lane except a rare
// cross-lane max bump (defer-max, THR=8) and one l-reduction at the end.
// P bounced through XOR-swizzled LDS (write 2-way, read at b128 floor).
// ---------------------------------------------------------------------------
__global__ __launch_bounds__(256) void attn_kernel(
    const bf16_t* __restrict__ Qb, const bf16_t* __restrict__ Kb,
    const bf16_t* __restrict__ Vt, bf16_t* __restrict__ Yb)
{
  __shared__ __align__(16) bf16_t plds[4][16][64];   // 8 KB, XOR-swizzled
  const int tid  = threadIdx.x;
  const int wave = tid >> 6, lane = tid & 63;
  const int lg = lane >> 4, li = lane & 15;
  const int gid = blockIdx.x;
  const int qt = (gid >> 3) & 15;
  const int bh = ((gid >> 7) << 3) | (gid & 7);   // blocks of one bh: same XCD
  const int b  = bh >> 3, hh = bh & 7;
  const int tok0 = b*1024 + qt*64 + wave*16;

  // B-operand: Q^T[d][q], lane holds q=li, d = lg*8..+7 (pre-scaled, exp2 dom)
  const bf16x8 qf = *reinterpret_cast<const bf16x8*>(
      Qb + (size_t)(tok0 + li)*256 + hh*32 + lg*8);

  // per-lane base pointers
  const bf16_t* Kp = Kb + (size_t)(b*1024 + li)*256 + hh*32 + lg*8; // + k*256
  const bf16_t* Vp = Vt + ((size_t)bh*32 + li)*1024 + lg*8;        // + mc*64 ..

  // swizzled LDS byte offsets (consistent XOR on write & read)
  char* pbase = (char*)&plds[wave][0][0];
  int wroff[4], roff[2];
  #pragma unroll
  for (int ct = 0; ct < 4; ++ct)
    wroff[ct] = (li*128 + ct*32 + lg*8) ^ ((li & 7) << 4);
  #pragma unroll
  for (int kk = 0; kk < 2; ++kk)
    roff[kk] = (li*128 + kk*64 + lg*16) ^ ((li & 7) << 4);

  const f32x4 fz = {0.f, 0.f, 0.f, 0.f};
  f32x4 acc0 = fz, acc1 = fz;        // Y^T: d = lg*4+r (+16), q = li
  float m = 0.f;                     // defer-max running max (log2 domain)
  float lrow = 0.f;                  // per-lane PARTIAL row sum (own 16 ks)

  bf16x8 kf[2][4];
  #pragma unroll
  for (int ct = 0; ct < 4; ++ct)
    kf[0][ct] = *reinterpret_cast<const bf16x8*>(Kp + (size_t)(ct*16)*256);

  #pragma unroll
  for (int mc = 0; mc < 16; ++mc) {
    const int cur = mc & 1, nxt = cur ^ 1;
    // ---- QK^T from resident K frags ----
    f32x4 s[4];
    #pragma unroll
    for (int ct = 0; ct < 4; ++ct)
      s[ct] = __builtin_amdgcn_mfma_f32_16x16x32_bf16(kf[cur][ct], qf, fz, 0, 0, 0);
    // ---- V loads (current chunk; consumed after softmax) ----
    const bf16x8 v00 = *reinterpret_cast<const bf16x8*>(Vp + mc*64);
    const bf16x8 v01 = *reinterpret_cast<const bf16x8*>(Vp + mc*64 + 32);
    const bf16x8 v10 = *reinterpret_cast<const bf16x8*>(Vp + 16*1024 + mc*64);
    const bf16x8 v11 = *reinterpret_cast<const bf16x8*>(Vp + 16*1024 + mc*64 + 32);
    // ---- K prefetch (next chunk) ----
    if (mc < 15) {
      #pragma unroll
      for (int ct = 0; ct < 4; ++ct)
        kf[nxt][ct] = *reinterpret_cast<const bf16x8*>(
            Kp + (size_t)((mc+1)*64 + ct*16)*256);
    }
    // ---- defer-max softmax (per-lane; cross-lane only on rare bump) ----
    float pmax = fmaxf(
        fmaxf(fmaxf(fmaxf(s[0][0], s[0][1]), fmaxf(s[0][2], s[0][3])),
              fmaxf(fmaxf(s[1][0], s[1][1]), fmaxf(s[1][2], s[1][3]))),
        fmaxf(fmaxf(fmaxf(s[2][0], s[2][1]), fmaxf(s[2][2], s[2][3])),
              fmaxf(fmaxf(s[3][0], s[3][1]), fmaxf(s[3][2], s[3][3]))));
    if (!__all(pmax - m <= 8.0f)) {
      float rmx = pmax;
      rmx = fmaxf(rmx, __shfl_xor(rmx, 16));
      rmx = fmaxf(rmx, __shfl_xor(rmx, 32));
      const float mnew = fmaxf(m, rmx);
      const float sf = fexp2(m - mnew);
      lrow *= sf;
      #pragma unroll
      for (int r = 0; r < 4; ++r) { acc0[r] *= sf; acc1[r] *= sf; }
      m = mnew;
    }
    float psum = 0.f;
    #pragma unroll
    for (int ct = 0; ct < 4; ++ct) {
      #pragma unroll
      for (int r = 0; r < 4; ++r)
        s[ct][r] = fexp2(s[ct][r] - m);
      psum += (s[ct][0] + s[ct][1]) + (s[ct][2] + s[ct][3]);
    }
    // ---- P^T -> swizzled LDS (8B stores, 2-way banks) ----
    #pragma unroll
    for (int ct = 0; ct < 4; ++ct) {
      union { bf16_t h4[4]; unsigned long long u; } pk;
      #pragma unroll
      for (int r = 0; r < 4; ++r) pk.h4[r] = (bf16_t)s[ct][r];
      *reinterpret_cast<unsigned long long*>(pbase + wroff[ct]) = pk.u;
    }
    lrow += psum;                       // independent work hides part of drain
    asm volatile("s_waitcnt lgkmcnt(0)" ::: "memory");  // own-region RAW drain
    // ---- PV: A = V^T (rows d), B = P^T (cols q) ----
    const bf16x8 pf0 = *reinterpret_cast<const bf16x8*>(pbase + roff[0]);
    const bf16x8 pf1 = *reinterpret_cast<const bf16x8*>(pbase + roff[1]);
    acc0 = __builtin_amdgcn_mfma_f32_16x16x32_bf16(v00, pf0, acc0, 0, 0, 0);
    acc0 = __builtin_amdgcn_mfma_f32_16x16x32_bf16(v01, pf1, acc0, 0, 0, 0);
    acc1 = __builtin_amdgcn_mfma_f32_16x16x32_bf16(v10, pf0, acc1, 0, 0, 0);
    acc1 = __builtin_amdgcn_mfma_f32_16x16x32_bf16(v11, pf1, acc1, 0, 0, 0);
  }

  // ---- single end-of-loop l reduction across the 4 lg lanes ----
  float lsum = lrow;
  lsum += __shfl_xor(lsum, 16);
  lsum += __shfl_xor(lsum, 32);
  const float inv = 1.0f / lsum;
  union { bf16_t h4[4]; unsigned long long u; } o0, o1;
  #pragma unroll
  for (int r = 0; r < 4; ++r) {
    o0.h4[r] = (bf16_t)(acc0[r]*inv);
    o1.h4[r] = (bf16_t)(acc1[r]*inv);
  }
  bf16_t* yp = Yb + (size_t)(tok0 + li)*256 + hh*32;
  *reinterpret_cast<unsigned long long*>(yp + lg*4)      = o0.u;
  *reinterpret_cast<unsigned long long*>(yp + 16 + lg*4) = o1.u;
}

// ---------------------------------------------------------------------------
extern "C" void kernel_launch(void* const* d_in, const int* in_sizes, int n_in,
                              void* d_out, int out_size, void* d_ws, size_t ws_size,
                              hipStream_t stream) {
  const float* x     = (const float*)d_in[0];
  const float* gamma = (const float*)d_in[1];
  const float* beta  = (const float*)d_in[2];
  const float* Wq    = (const float*)d_in[3];
  const float* bq    = (const float*)d_in[4];
  const float* Wk    = (const float*)d_in[5];
  const float* bk    = (const float*)d_in[6];
  const float* Wv    = (const float*)d_in[7];
  const float* bv    = (const float*)d_in[8];
  const float* Wp    = (const float*)d_in[9];
  const float* bp    = (const float*)d_in[10];
  float* out = (float*)d_out;

  char* ws = (char*)d_ws;
  bf16_t* Wt  = (bf16_t*)(ws);              // 4 * 65536 bf16 = 512 KB
  bf16_t* Xln = (bf16_t*)(ws + 524288);     // 16384*256 bf16 = 8 MB
  bf16_t* Qb  = (bf16_t*)(ws + 8912896);    // 8 MB
  bf16_t* Kb  = (bf16_t*)(ws + 17301504);   // 8 MB
  bf16_t* Vt  = (bf16_t*)(ws + 25690112);   // 8 MB  (total 32.5 MB)
  bf16_t* Yb  = Xln;                        // alias: Xln dead after QKV GEMM

  wtr_kernel<<<1024, 256, 0, stream>>>(Wq, Wk, Wv, Wp, Wt);
  ln_kernel<<<4096, 256, 0, stream>>>(x, gamma, beta, Xln);
  gemm_kernel<0><<<dim3(128, 6), 256, 0, stream>>>(
      Xln, Wt, bq, bk, bv, Qb, Kb, Vt, nullptr);
  attn_kernel<<<2048, 256, 0, stream>>>(Qb, Kb, Vt, Yb);
  gemm_kernel<1><<<dim3(128, 2), 256, 0, stream>>>(
      Yb, Wt + 3*65536, bp, nullptr, nullptr, nullptr, nullptr, nullptr, out);
}